// Round 11
// baseline (895.183 us; speedup 1.0000x reference)
//
#include <hip/hip_runtime.h>
#include <hip/hip_bf16.h>

using bf16 = __hip_bfloat16;
typedef __attribute__((ext_vector_type(8))) short short8;
typedef __attribute__((ext_vector_type(4))) float f32x4;
typedef __attribute__((ext_vector_type(4))) int i32x4;

#define QP   960
#define QO   896
#define KTOT 2304
#define NIMG 64
#define CCH  256
#define HW   28
#define PLN  784

__device__ __forceinline__ void gload_lds16(const void* g, void* l) {
  __builtin_amdgcn_global_load_lds((const __attribute__((address_space(1))) void*)g,
                                   (__attribute__((address_space(3))) void*)l, 16, 0, 0);
}

// ------- init: zero Xp borders/tails (i8) + zero rs1/rs2 --------------------
__global__ __launch_bounds__(256) void kinit(int8_t* __restrict__ xp1,
                                             int8_t* __restrict__ xp2,
                                             i32x4* __restrict__ rsz) {
  const int b = blockIdx.x;
  const int t = threadIdx.x;
  const i32x4 z = {0, 0, 0, 0};
  if (b < 128) {
    const int n = b >> 1;
    int8_t* xp = (b & 1) ? xp2 : xp1;
#pragma unroll
    for (int p = 0; p < 11; ++p) {
      const int task = p * 256 + t;
      const int r = task >> 4, l16 = task & 15;
      int q;
      if (r < 30) q = r;
      else if (r < 60) q = 870 + (r - 30);
      else if (r < 120) q = 900 + (r - 60);
      else { const int k = r - 120; q = (1 + (k >> 1)) * 30 + ((k & 1) ? 29 : 0); }
      ((i32x4*)(xp + ((size_t)n * QP + q) * CCH))[l16] = z;
    }
  } else {
    rsz[(b - 128) * 256 + t] = z;
  }
}

// ---------------- weight prep ------------------------------------------------
__global__ __launch_bounds__(256) void kwprep(const float* __restrict__ w1,
                                              const float* __restrict__ w2,
                                              int8_t* __restrict__ aw1,
                                              int8_t* __restrict__ aw2,
                                              float* __restrict__ am1,
                                              float* __restrict__ am2) {
  const int o = blockIdx.x & 255;
  const float* w = (blockIdx.x >> 8) ? w2 : w1;
  int8_t* aw = (blockIdx.x >> 8) ? aw2 : aw1;
  float* am = (blockIdx.x >> 8) ? am2 : am1;
  const int t = threadIdx.x;
  const int lane = t & 63, wid = t >> 6;
  const float* wo = w + (size_t)o * KTOT;
  float v[9];
  double s = 0.0;
#pragma unroll
  for (int j = 0; j < 9; ++j) { v[j] = wo[t * 9 + j]; s += (double)v[j]; }
  __shared__ double red[4];
#pragma unroll
  for (int m = 32; m >= 1; m >>= 1) s += __shfl_xor(s, m);
  if (lane == 0) red[wid] = s;
  __syncthreads();
  const double mean = (red[0] + red[1] + red[2] + red[3]) * (1.0 / 2304.0);
  __syncthreads();
  double sq = 0.0;
#pragma unroll
  for (int j = 0; j < 9; ++j) { const double d = (double)v[j] - mean; sq += d * d; }
#pragma unroll
  for (int m = 32; m >= 1; m >>= 1) sq += __shfl_xor(sq, m);
  if (lane == 0) red[wid] = sq;
  __syncthreads();
  const double alpha = sqrt((red[0] + red[1] + red[2] + red[3]) * (1.0 / 2304.0));
#pragma unroll
  for (int j = 0; j < 9; ++j) {
    const double d = (double)v[j] - mean;
    const int sg = d > 0.0 ? 1 : (d < 0.0 ? -1 : 0);
    aw[(size_t)o * KTOT + j * CCH + t] = (int8_t)sg;
  }
  if (t == 0) { am[o] = (float)alpha; am[CCH + o] = (float)mean; }
}

// -------- activation signs + row sums + transposed residual -----------------
__global__ __launch_bounds__(256) void kaprep(const float* __restrict__ x,
                                              const float* __restrict__ alpha,
                                              const float* __restrict__ beta,
                                              int8_t* __restrict__ xp,
                                              float* __restrict__ rs,
                                              float* __restrict__ xT) {
  const int n = blockIdx.x / HW;
  const int h = blockIdx.x % HW;
  const int c = threadIdx.x;
  const float a = alpha[c], bt = beta[c];
  const float* src = x + ((size_t)(n * CCH + c)) * PLN + h * HW;
  __shared__ int8_t tile[CCH][HW];
#pragma unroll
  for (int j = 0; j < 7; ++j) {
    float4 f = ((const float4*)src)[j];
    float vv[4] = {f.x, f.y, f.z, f.w};
#pragma unroll
    for (int e = 0; e < 4; ++e) {
      const float xa = (vv[e] - bt) / a;
      const float sg = xa > 0.f ? 1.f : (xa < 0.f ? -1.f : 0.f);
      tile[c][j * 4 + e] = (int8_t)__float2int_rn(sg * a + bt);
      xT[((size_t)n * PLN + h * HW + j * 4 + e) * CCH + c] = vv[e];
    }
  }
  __syncthreads();
  int8_t* dst = xp + ((size_t)n * QP + (h + 1) * 30 + 1) * CCH;
#pragma unroll
  for (int ww = 0; ww < HW; ++ww) dst[ww * CCH + c] = tile[c][ww];
  const int ww = c >> 3, sub = c & 7;
  if (ww < HW) {
    int s = 0;
#pragma unroll
    for (int cc = 0; cc < 32; ++cc) s += (int)tile[sub * 32 + cc][ww];
    s += __shfl_xor(s, 4); s += __shfl_xor(s, 2); s += __shfl_xor(s, 1);
    if (sub == 0) rs[(size_t)n * QP + (h + 1) * 30 + 1 + ww] = (float)s;
  }
}

// ---------------- kconv: r9-verified (persistent A + B 3-ring) --------------
template <int EPI>
__global__ __launch_bounds__(256, 2) void kconv(
    const int8_t* __restrict__ xp, const int8_t* __restrict__ aw,
    const float* __restrict__ am, const float* __restrict__ rs,
    const float* __restrict__ bng, const float* __restrict__ bnb,
    const float* __restrict__ bnm, const float* __restrict__ bnv,
    const float* __restrict__ pos, const float* __restrict__ neg,
    const float* __restrict__ xT, const bf16* __restrict__ x1r,
    const float* __restrict__ a2, const float* __restrict__ b2,
    int8_t* __restrict__ xpn, bf16* __restrict__ x1t,
    float* __restrict__ rsn, float* __restrict__ out)
{
  __shared__ char lds[73728];
  char* ldsB = lds + 49152;
  const int bid0 = blockIdx.x;
  const int bid = (bid0 & 7) * 112 + (bid0 >> 3);
  const int nt = bid & 1;
  const int mt = bid >> 1;
  const int n = mt / 7;
  const int qt = (mt % 7) * 128;
  const int o0 = nt * 128;
  const int t = threadIdx.x;
  const int lane = t & 63, wid = t >> 6;
  const int wp = (wid >> 1) * 64, wo = (wid & 1) * 64;

  const int rowp = t >> 3;
  const int pcS = t & 7;
  const int cS = pcS ^ (rowp & 7);
  const int pS = cS >> 2;
  const int k16S = cS & 3;

  i32x4 acc[4][4];
#pragma unroll
  for (int i = 0; i < 4; ++i)
#pragma unroll
    for (int j = 0; j < 4; ++j) acc[i][j] = (i32x4){0, 0, 0, 0};

  const int r16 = lane & 15;
  const int g = lane >> 4;
  const int g4 = g * 4;
  const int rsh = r16 >> 1;
  const int pc0 = ((r16 & 1) * 4 + g) ^ rsh;
  const int wpH = (wid >> 1) * 32, woH = (wid & 1) * 32;
  const int qoff = (EPI == 1) ? wp : wo;
  const int ooffH = (EPI == 1) ? woH : wpH;

  const int8_t* baseB = aw + ((size_t)(o0 + 2 * rowp + pS)) * KTOT + k16S * 16;

  auto STAGE_B = [&](int buf, int ks) {
    const int8_t* sB = baseB + (size_t)ks * 64;
    char* dB = ldsB + buf * 8192;
    const int d0 = rowp * 128 + pcS * 16;
    gload_lds16(sB, dB + d0);
    gload_lds16(sB + (size_t)64 * KTOT, dB + 4096 + d0);
  };

  {
    const int8_t* imgA = xp + ((size_t)(n * QP + qt)) * CCH;
#pragma unroll
    for (int i = 0; i < 12; ++i) {
      const int task = t + i * 256;
      if (task < 3040) {
        const int rr = task >> 4, pc = task & 15;
        gload_lds16(imgA + (size_t)rr * CCH + ((pc ^ (rr & 15)) * 16),
                    lds + rr * 256 + pc * 16);
      }
    }
  }
  STAGE_B(0, 0);
  STAGE_B(1, 1);
  asm volatile("s_waitcnt vmcnt(2)" ::: "memory");
  __builtin_amdgcn_s_barrier();

#pragma unroll
  for (int ks = 0; ks < 36; ++ks) {
    const int tap = ks >> 2, ksl = ks & 3;
    const int shc = (tap / 3) * 30 + (tap % 3);
    const int cur = ks % 3;
    const int achunk = ((ksl * 4 + g) ^ ((r16 + shc) & 15)) * 16;
    const char* pAr = lds + (shc + qoff + r16) * 256 + achunk;
    const char* pB = ldsB + cur * 8192;
    i32x4 fP[4], fW[4];
#pragma unroll
    for (int m = 0; m < 4; ++m) {
      fP[m] = *(const i32x4*)&pAr[m * 4096];
      fW[m] = *(const i32x4*)&pB[(ooffH + m * 8 + rsh) * 128 + pc0 * 16];
    }
    if (ks < 34) STAGE_B((ks + 2) % 3, ks + 2);
    __builtin_amdgcn_s_setprio(1);
    if constexpr (EPI == 1) {
#pragma unroll
      for (int m = 0; m < 4; ++m)
#pragma unroll
        for (int nn = 0; nn < 4; ++nn)
          acc[m][nn] = __builtin_amdgcn_mfma_i32_16x16x64_i8(
              fP[m], fW[nn], acc[m][nn], 0, 0, 0);
    } else {
#pragma unroll
      for (int m = 0; m < 4; ++m)
#pragma unroll
        for (int nn = 0; nn < 4; ++nn)
          acc[m][nn] = __builtin_amdgcn_mfma_i32_16x16x64_i8(
              fW[m], fP[nn], acc[m][nn], 0, 0, 0);
    }
    __builtin_amdgcn_s_setprio(0);
    if (ks < 34) {
      asm volatile("s_waitcnt vmcnt(2)" ::: "memory");
    } else {
      asm volatile("s_waitcnt vmcnt(0)" ::: "memory");
    }
    __builtin_amdgcn_s_barrier();
  }

  if constexpr (EPI == 1) {
    int oc[4];
    float invc[4], addc[4], ppc[4], ngc[4], awc[4], mwc[4], aac[4], bbc[4];
#pragma unroll
    for (int nn = 0; nn < 4; ++nn) {
      const int o = o0 + wo + nn * 16 + r16;
      oc[nn] = o;
      const float inv = bng[o] / sqrtf(bnv[o] + 1e-5f);
      invc[nn] = inv;
      addc[nn] = bnb[o] - bnm[o] * inv;
      ppc[nn] = pos[o]; ngc[nn] = neg[o];
      awc[nn] = am[o];  mwc[nn] = am[CCH + o];
      aac[nn] = a2[o];  bbc[nn] = b2[o];
    }
    short* tb = (short*)lds;
#pragma unroll
    for (int m = 0; m < 4; ++m) {
#pragma unroll
      for (int r = 0; r < 4; ++r) {
        const int ql = wp + m * 16 + g4 + r;
        const int q = qt + ql;
        const int hh = q / 30, ww2 = q % 30;
        if (hh < HW && ww2 < HW) {
          const float* rrow = rs + (size_t)n * QP + q;
          float tq = 0.f;
#pragma unroll
          for (int kh = 0; kh < 3; ++kh)
#pragma unroll
            for (int kw = 0; kw < 3; ++kw) tq += rrow[kh * 30 + kw];
          const float* xrow = xT + ((size_t)n * PLN + hh * HW + ww2) * CCH;
          float rowsum = 0.f;
#pragma unroll
          for (int nn = 0; nn < 4; ++nn) {
            const int o = oc[nn];
            float v = awc[nn] * (float)acc[m][nn][r] + mwc[nn] * tq;
            v = v * invc[nn] + addc[nn];
            v += xrow[o];
            v = v > 0.f ? ppc[nn] * v : ngc[nn] * v;
            const float xa = (v - bbc[nn]) / aac[nn];
            const float sg = xa > 0.f ? 1.f : (xa < 0.f ? -1.f : 0.f);
            const float bv = sg * aac[nn] + bbc[nn];
            rowsum += bv;
            xpn[((size_t)n * QP + (hh + 1) * 30 + (ww2 + 1)) * CCH + o] =
                (int8_t)__float2int_rn(bv);
            bf16 hb = __float2bfloat16(v);
            tb[(wo + nn * 16 + r16) * 136 + ql] = *reinterpret_cast<short*>(&hb);
          }
          rowsum += __shfl_xor(rowsum, 8); rowsum += __shfl_xor(rowsum, 4);
          rowsum += __shfl_xor(rowsum, 2); rowsum += __shfl_xor(rowsum, 1);
          if (r16 == 0)
            atomicAdd(&rsn[(size_t)n * QP + (hh + 1) * 30 + (ww2 + 1)], rowsum);
        }
      }
    }
    __syncthreads();
    {
      const int o_l = t >> 1, half = t & 1;
      short* x1s = (short*)x1t;
      const size_t gbase = ((size_t)(n * CCH + o0 + o_l)) * QO + qt + half * 64;
#pragma unroll
      for (int j = 0; j < 8; ++j)
        *(short8*)(x1s + gbase + j * 8) = *(const short8*)&tb[o_l * 136 + half * 64 + j * 8];
    }
  } else {
    float* cst = (float*)lds;
    if (t < 128) {
      const int o = o0 + t;
      const float inv = bng[o] / sqrtf(bnv[o] + 1e-5f);
      cst[t]       = am[o] * inv;
      cst[128 + t] = am[CCH + o] * inv;
      cst[256 + t] = bnb[o] - bnm[o] * inv;
      cst[384 + t] = pos[o];
      cst[512 + t] = neg[o];
    }
    __syncthreads();
    const int c16 = lane & 15;
#pragma unroll
    for (int nn = 0; nn < 4; ++nn) {
      const int q = qt + wo + nn * 16 + c16;
      const int hh = q / 30, ww2 = q % 30;
      const bool valid = (hh < HW) && (ww2 < HW);
      const float* rrow = rs + (size_t)n * QP + q;
      float tq = 0.f;
#pragma unroll
      for (int kh = 0; kh < 3; ++kh)
#pragma unroll
        for (int kw = 0; kw < 3; ++kw) tq += rrow[kh * 30 + kw];
#pragma unroll
      for (int m = 0; m < 4; ++m) {
#pragma unroll
        for (int r = 0; r < 4; ++r) {
          const int ol = wp + m * 16 + g4 + r;
          const int o = o0 + ol;
          if (valid) {
            float v = cst[ol] * (float)acc[m][nn][r] + cst[128 + ol] * tq + cst[256 + ol];
            v += __bfloat162float(x1r[((size_t)(n * CCH + o)) * QO + q]);
            v = v > 0.f ? cst[384 + ol] * v : cst[512 + ol] * v;
            out[((size_t)(n * CCH + o)) * PLN + hh * HW + ww2] = v;
          }
        }
      }
    }
  }
}

// ---------------- DIAGNOSTIC PROBES (run after the real pipeline) -----------
// Clones of kconv<1>'s loop with one phase removed; write only dead ws
// buffers; J-repeated so each probe lands in the rocprof top-5.
template <int SKIPB, int SKIPA, int SKIPM, int PURE, int J>
__global__ __launch_bounds__(256, 2) void kprobe(
    const int8_t* __restrict__ xp, const int8_t* __restrict__ aw,
    const float* __restrict__ am, const float* __restrict__ rs,
    const float* __restrict__ xT, const float* __restrict__ a2,
    const float* __restrict__ b2, int8_t* __restrict__ xpn,
    bf16* __restrict__ x1t, float* __restrict__ rsn)
{
  __shared__ char lds[73728];
  char* ldsB = lds + 49152;
  const int bid0 = blockIdx.x;
  const int bid = (bid0 & 7) * 112 + (bid0 >> 3);
  const int nt = bid & 1;
  const int mt = bid >> 1;
  const int n = mt / 7;
  const int qt = (mt % 7) * 128;
  const int o0 = nt * 128;
  const int t = threadIdx.x;
  const int lane = t & 63, wid = t >> 6;
  const int wp = (wid >> 1) * 64, wo = (wid & 1) * 64;
  const int rowp = t >> 3, pcS = t & 7;
  const int cS = pcS ^ (rowp & 7);
  const int pS = cS >> 2, k16S = cS & 3;

  i32x4 acc[4][4];
#pragma unroll
  for (int i = 0; i < 4; ++i)
#pragma unroll
    for (int j = 0; j < 4; ++j) acc[i][j] = (i32x4){0, 0, 0, 0};

  const int r16 = lane & 15;
  const int g = lane >> 4;
  const int g4 = g * 4;
  const int rsh = r16 >> 1;
  const int pc0 = ((r16 & 1) * 4 + g) ^ rsh;
  const int woH = (wid & 1) * 32;

  const int8_t* baseB = aw + ((size_t)(o0 + 2 * rowp + pS)) * KTOT + k16S * 16;
  auto STAGE_B = [&](int buf, int ks) {
    const int8_t* sB = baseB + (size_t)ks * 64;
    char* dB = ldsB + buf * 8192;
    const int d0 = rowp * 128 + pcS * 16;
    gload_lds16(sB, dB + d0);
    gload_lds16(sB + (size_t)64 * KTOT, dB + 4096 + d0);
  };

  {
    const int8_t* imgA = xp + ((size_t)(n * QP + qt)) * CCH;
#pragma unroll
    for (int i = 0; i < 12; ++i) {
      const int task = t + i * 256;
      if (task < 3040) {
        const int rr = task >> 4, pc = task & 15;
        gload_lds16(imgA + (size_t)rr * CCH + ((pc ^ (rr & 15)) * 16),
                    lds + rr * 256 + pc * 16);
      }
    }
  }
  STAGE_B(0, 0);
  STAGE_B(1, 1);
  asm volatile("s_waitcnt vmcnt(0)" ::: "memory");
  __builtin_amdgcn_s_barrier();

  // pre-loaded fragments for SKIPA / PURE modes
  i32x4 fPc[4], fWc[4];
#pragma unroll
  for (int m = 0; m < 4; ++m) {
    fPc[m] = *(const i32x4*)&lds[(wp + r16) * 256 + ((g) ^ (r16 & 15)) * 16 + m * 4096];
    fWc[m] = *(const i32x4*)&ldsB[(woH + m * 8 + rsh) * 128 + pc0 * 16];
  }
  int chk = 0;

#pragma unroll 1
  for (int j = 0; j < J; ++j) {
#pragma unroll
    for (int ks = 0; ks < 36; ++ks) {
      const int tap = ks >> 2, ksl = ks & 3;
      const int shc = (tap / 3) * 30 + (tap % 3);
      const int cur = ks % 3;
      i32x4 fP[4], fW[4];
      if constexpr (!PURE) {
        if constexpr (!SKIPA) {
          const int achunk = ((ksl * 4 + g) ^ ((r16 + shc) & 15)) * 16;
          const char* pAr = lds + (shc + wp + r16) * 256 + achunk;
#pragma unroll
          for (int m = 0; m < 4; ++m) fP[m] = *(const i32x4*)&pAr[m * 4096];
        } else {
#pragma unroll
          for (int m = 0; m < 4; ++m) fP[m] = fPc[m];
        }
        const char* pB = ldsB + cur * 8192;
#pragma unroll
        for (int m = 0; m < 4; ++m)
          fW[m] = *(const i32x4*)&pB[(woH + m * 8 + rsh) * 128 + pc0 * 16];
        if constexpr (!SKIPB) { if (ks < 34) STAGE_B((ks + 2) % 3, ks + 2); }
      } else {
#pragma unroll
        for (int m = 0; m < 4; ++m) { fP[m] = fPc[m]; fW[m] = fWc[m]; }
      }
      if constexpr (!SKIPM) {
        __builtin_amdgcn_s_setprio(1);
#pragma unroll
        for (int m = 0; m < 4; ++m)
#pragma unroll
          for (int nn = 0; nn < 4; ++nn)
            acc[m][nn] = __builtin_amdgcn_mfma_i32_16x16x64_i8(
                fP[m], fW[nn], acc[m][nn], 0, 0, 0);
        __builtin_amdgcn_s_setprio(0);
      } else {
#pragma unroll
        for (int m = 0; m < 4; ++m) { chk += fP[m][0] + fW[m][0]; }
      }
      if constexpr (!PURE) {
        if constexpr (!SKIPB) {
          if (ks < 34) { asm volatile("s_waitcnt vmcnt(2)" ::: "memory"); }
          else         { asm volatile("s_waitcnt vmcnt(0)" ::: "memory"); }
        }
        __builtin_amdgcn_s_barrier();
      }
    }
  }
  if (chk == 0x13579b) ((int*)rsn)[t] = chk;   // keep-alive, data-dependent

  // epilogue (same cost as kconv<1>; writes DEAD buffers xpn/x1t/rsn)
  float awc[4], mwc[4], aac[4], bbc[4];
  int oc[4];
#pragma unroll
  for (int nn = 0; nn < 4; ++nn) {
    const int o = o0 + wo + nn * 16 + r16;
    oc[nn] = o; awc[nn] = am[o]; mwc[nn] = am[CCH + o];
    aac[nn] = a2[o]; bbc[nn] = b2[o];
  }
  __syncthreads();
  short* tb = (short*)lds;
#pragma unroll
  for (int m = 0; m < 4; ++m) {
#pragma unroll
    for (int r = 0; r < 4; ++r) {
      const int ql = wp + m * 16 + g4 + r;
      const int q = qt + ql;
      const int hh = q / 30, ww2 = q % 30;
      if (hh < HW && ww2 < HW) {
        const float* rrow = rs + (size_t)n * QP + q;
        float tq = 0.f;
#pragma unroll
        for (int kh = 0; kh < 3; ++kh)
#pragma unroll
          for (int kw = 0; kw < 3; ++kw) tq += rrow[kh * 30 + kw];
        const float* xrow = xT + ((size_t)n * PLN + hh * HW + ww2) * CCH;
        float rowsum = 0.f;
#pragma unroll
        for (int nn = 0; nn < 4; ++nn) {
          const int o = oc[nn];
          float v = awc[nn] * (float)acc[m][nn][r] + mwc[nn] * tq + xrow[o];
          const float sg = v > bbc[nn] ? 1.f : -1.f;
          const float bv = sg * aac[nn] + bbc[nn];
          rowsum += bv;
          xpn[((size_t)n * QP + (hh + 1) * 30 + (ww2 + 1)) * CCH + o] =
              (int8_t)__float2int_rn(bv);
          bf16 hb = __float2bfloat16(v);
          tb[(wo + nn * 16 + r16) * 136 + ql] = *reinterpret_cast<short*>(&hb);
        }
        rowsum += __shfl_xor(rowsum, 8); rowsum += __shfl_xor(rowsum, 4);
        rowsum += __shfl_xor(rowsum, 2); rowsum += __shfl_xor(rowsum, 1);
        if (r16 == 0)
          atomicAdd(&rsn[(size_t)n * QP + (hh + 1) * 30 + (ww2 + 1)], rowsum);
      }
    }
  }
  __syncthreads();
  {
    const int o_l = t >> 1, half = t & 1;
    short* x1s = (short*)x1t;
    const size_t gbase = ((size_t)(n * CCH + o0 + o_l)) * QO + qt + half * 64;
#pragma unroll
    for (int j = 0; j < 8; ++j)
      *(short8*)(x1s + gbase + j * 8) = *(const short8*)&tb[o_l * 136 + half * 64 + j * 8];
  }
}

extern "C" void kernel_launch(void* const* d_in, const int* in_sizes, int n_in,
                              void* d_out, int out_size, void* d_ws, size_t ws_size,
                              hipStream_t stream) {
  const float* x   = (const float*)d_in[0];
  const float* w1  = (const float*)d_in[1];
  const float* al1 = (const float*)d_in[2];
  const float* be1 = (const float*)d_in[3];
  const float* g1  = (const float*)d_in[4];
  const float* bb1 = (const float*)d_in[5];
  const float* m1  = (const float*)d_in[6];
  const float* v1  = (const float*)d_in[7];
  const float* p1  = (const float*)d_in[8];
  const float* n1  = (const float*)d_in[9];
  const float* w2  = (const float*)d_in[10];
  const float* al2 = (const float*)d_in[11];
  const float* be2 = (const float*)d_in[12];
  const float* g2  = (const float*)d_in[13];
  const float* bb2 = (const float*)d_in[14];
  const float* m2  = (const float*)d_in[15];
  const float* v2  = (const float*)d_in[16];
  const float* p2  = (const float*)d_in[17];
  const float* n2  = (const float*)d_in[18];
  float* out = (float*)d_out;

  char* ws = (char*)d_ws;
  int8_t* Xp1 = (int8_t*)(ws);
  int8_t* Xp2 = (int8_t*)(ws + 15728640);
  bf16*   X1T = (bf16*)(ws + 31457280);
  int8_t* Aw1 = (int8_t*)(ws + 60817408);
  int8_t* Aw2 = (int8_t*)(ws + 61407232);
  float*  am1 = (float*)(ws + 61997056);
  float*  am2 = (float*)(ws + 61999104);
  float*  rs1 = (float*)(ws + 62001152);
  float*  rs2 = (float*)(ws + 62246912);
  float*  xT  = out;

  kinit<<<248, 256, 0, stream>>>(Xp1, Xp2, (i32x4*)rs1);
  kwprep<<<512, 256, 0, stream>>>(w1, w2, Aw1, Aw2, am1, am2);
  kaprep<<<NIMG * HW, 256, 0, stream>>>(x, al1, be1, Xp1, rs1, xT);
  kconv<1><<<896, 256, 0, stream>>>(Xp1, Aw1, am1, rs1, g1, bb1, m1, v1, p1, n1,
                                    xT, nullptr, al2, be2, Xp2, X1T, rs2, nullptr);
  kconv<2><<<896, 256, 0, stream>>>(Xp2, Aw2, am2, rs2, g2, bb2, m2, v2, p2, n2,
                                    nullptr, X1T, nullptr, nullptr, nullptr, nullptr,
                                    nullptr, out);

  // -------- diagnostic probes (dead outputs; after real pipeline) ----------
  // order: full, noBstage, noAread, noMFMA, pureMFMA
  kprobe<0,0,0,0,4><<<896, 256, 0, stream>>>(Xp1, Aw1, am1, rs1, xT, al2, be2,
                                             Xp1, X1T, rs1);
  kprobe<1,0,0,0,4><<<896, 256, 0, stream>>>(Xp1, Aw1, am1, rs1, xT, al2, be2,
                                             Xp1, X1T, rs1);
  kprobe<0,1,0,0,4><<<896, 256, 0, stream>>>(Xp1, Aw1, am1, rs1, xT, al2, be2,
                                             Xp1, X1T, rs1);
  kprobe<0,0,1,0,4><<<896, 256, 0, stream>>>(Xp1, Aw1, am1, rs1, xT, al2, be2,
                                             Xp1, X1T, rs1);
  kprobe<0,0,0,1,6><<<896, 256, 0, stream>>>(Xp1, Aw1, am1, rs1, xT, al2, be2,
                                             Xp1, X1T, rs1);
}

// Round 12
// 163.831 us; speedup vs baseline: 5.4641x; 5.4641x over previous
//
#include <hip/hip_runtime.h>
#include <hip/hip_bf16.h>

using bf16 = __hip_bfloat16;
typedef __attribute__((ext_vector_type(8))) short short8;
typedef __attribute__((ext_vector_type(4))) float f32x4;
typedef __attribute__((ext_vector_type(4))) int i32x4;

#define QP   960
#define QO   896
#define KTOT 2304
#define NIMG 64
#define CCH  256
#define HW   28
#define PLN  784

__device__ __forceinline__ void gload_lds16(const void* g, void* l) {
  __builtin_amdgcn_global_load_lds((const __attribute__((address_space(1))) void*)g,
                                   (__attribute__((address_space(3))) void*)l, 16, 0, 0);
}

// ------- init: zero Xp borders/tails (i8) + zero rs1/rs2 --------------------
__global__ __launch_bounds__(256) void kinit(int8_t* __restrict__ xp1,
                                             int8_t* __restrict__ xp2,
                                             i32x4* __restrict__ rsz) {
  const int b = blockIdx.x;
  const int t = threadIdx.x;
  const i32x4 z = {0, 0, 0, 0};
  if (b < 128) {
    const int n = b >> 1;
    int8_t* xp = (b & 1) ? xp2 : xp1;
#pragma unroll
    for (int p = 0; p < 11; ++p) {
      const int task = p * 256 + t;
      const int r = task >> 4, l16 = task & 15;
      int q;
      if (r < 30) q = r;
      else if (r < 60) q = 870 + (r - 30);
      else if (r < 120) q = 900 + (r - 60);
      else { const int k = r - 120; q = (1 + (k >> 1)) * 30 + ((k & 1) ? 29 : 0); }
      ((i32x4*)(xp + ((size_t)n * QP + q) * CCH))[l16] = z;
    }
  } else {
    rsz[(b - 128) * 256 + t] = z;
  }
}

// ---------------- weight prep ------------------------------------------------
__global__ __launch_bounds__(256) void kwprep(const float* __restrict__ w1,
                                              const float* __restrict__ w2,
                                              int8_t* __restrict__ aw1,
                                              int8_t* __restrict__ aw2,
                                              float* __restrict__ am1,
                                              float* __restrict__ am2) {
  const int o = blockIdx.x & 255;
  const float* w = (blockIdx.x >> 8) ? w2 : w1;
  int8_t* aw = (blockIdx.x >> 8) ? aw2 : aw1;
  float* am = (blockIdx.x >> 8) ? am2 : am1;
  const int t = threadIdx.x;
  const int lane = t & 63, wid = t >> 6;
  const float* wo = w + (size_t)o * KTOT;
  float v[9];
  double s = 0.0;
#pragma unroll
  for (int j = 0; j < 9; ++j) { v[j] = wo[t * 9 + j]; s += (double)v[j]; }
  __shared__ double red[4];
#pragma unroll
  for (int m = 32; m >= 1; m >>= 1) s += __shfl_xor(s, m);
  if (lane == 0) red[wid] = s;
  __syncthreads();
  const double mean = (red[0] + red[1] + red[2] + red[3]) * (1.0 / 2304.0);
  __syncthreads();
  double sq = 0.0;
#pragma unroll
  for (int j = 0; j < 9; ++j) { const double d = (double)v[j] - mean; sq += d * d; }
#pragma unroll
  for (int m = 32; m >= 1; m >>= 1) sq += __shfl_xor(sq, m);
  if (lane == 0) red[wid] = sq;
  __syncthreads();
  const double alpha = sqrt((red[0] + red[1] + red[2] + red[3]) * (1.0 / 2304.0));
#pragma unroll
  for (int j = 0; j < 9; ++j) {
    const double d = (double)v[j] - mean;
    const int sg = d > 0.0 ? 1 : (d < 0.0 ? -1 : 0);
    aw[(size_t)o * KTOT + j * CCH + t] = (int8_t)sg;
  }
  if (t == 0) { am[o] = (float)alpha; am[CCH + o] = (float)mean; }
}

// -------- activation signs + row sums + transposed residual -----------------
__global__ __launch_bounds__(256) void kaprep(const float* __restrict__ x,
                                              const float* __restrict__ alpha,
                                              const float* __restrict__ beta,
                                              int8_t* __restrict__ xp,
                                              float* __restrict__ rs,
                                              float* __restrict__ xT) {
  const int n = blockIdx.x / HW;
  const int h = blockIdx.x % HW;
  const int c = threadIdx.x;
  const float a = alpha[c], bt = beta[c];
  const float* src = x + ((size_t)(n * CCH + c)) * PLN + h * HW;
  __shared__ int8_t tile[CCH][HW];
#pragma unroll
  for (int j = 0; j < 7; ++j) {
    float4 f = ((const float4*)src)[j];
    float vv[4] = {f.x, f.y, f.z, f.w};
#pragma unroll
    for (int e = 0; e < 4; ++e) {
      const float xa = (vv[e] - bt) / a;
      const float sg = xa > 0.f ? 1.f : (xa < 0.f ? -1.f : 0.f);
      tile[c][j * 4 + e] = (int8_t)__float2int_rn(sg * a + bt);
      xT[((size_t)n * PLN + h * HW + j * 4 + e) * CCH + c] = vv[e];
    }
  }
  __syncthreads();
  int8_t* dst = xp + ((size_t)n * QP + (h + 1) * 30 + 1) * CCH;
#pragma unroll
  for (int ww = 0; ww < HW; ++ww) dst[ww * CCH + c] = tile[c][ww];
  const int ww = c >> 3, sub = c & 7;
  if (ww < HW) {
    int s = 0;
#pragma unroll
    for (int cc = 0; cc < 32; ++cc) s += (int)tile[sub * 32 + cc][ww];
    s += __shfl_xor(s, 4); s += __shfl_xor(s, 2); s += __shfl_xor(s, 1);
    if (sub == 0) rs[(size_t)n * QP + (h + 1) * 30 + 1 + ww] = (float)s;
  }
}

// ---------------- implicit-GEMM conv: barrier-free K-loop (r12) -------------
// Layout: B per-wave private rings [4 waves][2 slots][4KB] @ lds+0 (32KB);
// persistent A (190 rows x 256B, row-local chunk-XOR swizzle) @ lds+32768.
// Loop has NO s_barrier: each wave stages its own B slice (4 gload_lds) and
// waits only its own counted vmcnt. A is read-only after one prologue barrier.
template <int EPI>
__global__ __launch_bounds__(256, 2) void kconv(
    const int8_t* __restrict__ xp, const int8_t* __restrict__ aw,
    const float* __restrict__ am, const float* __restrict__ rs,
    const float* __restrict__ bng, const float* __restrict__ bnb,
    const float* __restrict__ bnm, const float* __restrict__ bnv,
    const float* __restrict__ pos, const float* __restrict__ neg,
    const float* __restrict__ xT, const bf16* __restrict__ x1r,
    const float* __restrict__ a2, const float* __restrict__ b2,
    int8_t* __restrict__ xpn, bf16* __restrict__ x1t,
    float* __restrict__ rsn, float* __restrict__ out)
{
  __shared__ char lds[81408];           // B rings 32KB @0 + A 47.5KB @32768
  char* ldsA = lds + 32768;
  const int bid0 = blockIdx.x;
  const int bid = (bid0 & 7) * 112 + (bid0 >> 3);   // bijective XCD swizzle
  const int nt = bid & 1;
  const int mt = bid >> 1;
  const int n = mt / 7;
  const int qt = (mt % 7) * 128;
  const int o0 = nt * 128;
  const int t = threadIdx.x;
  const int lane = t & 63, wid = t >> 6;
  const int wp = (wid >> 1) * 64, wo = (wid & 1) * 64;

  i32x4 acc[4][4];
#pragma unroll
  for (int i = 0; i < 4; ++i)
#pragma unroll
    for (int j = 0; j < 4; ++j) acc[i][j] = (i32x4){0, 0, 0, 0};

  const int r16 = lane & 15;
  const int g = lane >> 4;
  const int g4 = g * 4;
  const int rsh = r16 >> 1;
  const int pc0 = ((r16 & 1) * 4 + g) ^ rsh;   // B phys chunk for frag read
  // operand-block selection (r9-verified)
  const int qoff = (EPI == 1) ? wp : wo;               // pixel rows in A region
  const int oSlice = ((EPI == 1) ? (wid & 1) : (wid >> 1)) * 64;  // weight slice

  // per-wave B staging: lane -> (rowq, pcq); swizzle indep. of chunk c since
  // (c*8+rowq)&7 == rowq. Slot layout identical to r9's proven half-tile.
  const int rowq = lane >> 3, pcq = lane & 7;
  const int cSW = pcq ^ rowq, pSW = cSW >> 2, k16W = cSW & 3;
  const int8_t* wsrc0 = aw + (size_t)(o0 + oSlice + 2 * rowq + pSW) * KTOT + k16W * 16;
  char* wslot0 = lds + wid * 8192;

  auto STAGE_W = [&](int slot, int ks) {
    const int8_t* s = wsrc0 + (size_t)ks * 64;
    char* d = wslot0 + slot * 4096 + lane * 16;
#pragma unroll
    for (int c = 0; c < 4; ++c)
      gload_lds16(s + (size_t)(16 * c) * KTOT, d + c * 1024);
  };

  // ---- prologue: cooperative persistent-A stage (3040 tasks) + B(0),B(1)
  {
    const int8_t* imgA = xp + ((size_t)(n * QP + qt)) * CCH;
#pragma unroll
    for (int i = 0; i < 12; ++i) {
      const int task = t + i * 256;
      if (task < 3040) {
        const int rr = task >> 4, pc = task & 15;
        gload_lds16(imgA + (size_t)rr * CCH + ((pc ^ (rr & 15)) * 16),
                    ldsA + rr * 256 + pc * 16);
      }
    }
  }
  STAGE_W(0, 0);
  STAGE_W(1, 1);
  asm volatile("s_waitcnt vmcnt(0)" ::: "memory");
  __builtin_amdgcn_s_barrier();       // ONLY barrier before the epilogue

#pragma unroll
  for (int ks = 0; ks < 36; ++ks) {
    // top-issue: stage(ks+1) into slot (ks+1)&1 (read at iter ks-1 -> safe)
    if (ks >= 1 && ks + 1 <= 35) STAGE_W((ks + 1) & 1, ks + 1);
    if (ks >= 2) {
      if (ks < 35) { asm volatile("s_waitcnt vmcnt(4)" ::: "memory"); }
      else         { asm volatile("s_waitcnt vmcnt(0)" ::: "memory"); }
    }
    const int tap = ks >> 2, ksl = ks & 3;
    const int shc = (tap / 3) * 30 + (tap % 3);
    const int achunk = ((ksl * 4 + g) ^ ((r16 + shc) & 15)) * 16;
    const char* pAr = ldsA + (shc + qoff + r16) * 256 + achunk;
    const char* pW = wslot0 + (ks & 1) * 4096;
    i32x4 fP[4], fW[4];
#pragma unroll
    for (int m = 0; m < 4; ++m) {
      fP[m] = *(const i32x4*)&pAr[m * 4096];
      fW[m] = *(const i32x4*)&pW[(m * 8 + rsh) * 128 + pc0 * 16];
    }
    __builtin_amdgcn_s_setprio(1);
    if constexpr (EPI == 1) {
#pragma unroll
      for (int m = 0; m < 4; ++m)
#pragma unroll
        for (int nn = 0; nn < 4; ++nn)
          acc[m][nn] = __builtin_amdgcn_mfma_i32_16x16x64_i8(
              fP[m], fW[nn], acc[m][nn], 0, 0, 0);
    } else {
#pragma unroll
      for (int m = 0; m < 4; ++m)
#pragma unroll
        for (int nn = 0; nn < 4; ++nn)
          acc[m][nn] = __builtin_amdgcn_mfma_i32_16x16x64_i8(
              fW[m], fP[nn], acc[m][nn], 0, 0, 0);
    }
    __builtin_amdgcn_s_setprio(0);
  }

  __syncthreads();   // reconverge before LDS reuse in epilogues

  if constexpr (EPI == 1) {
    // D[q = qt+wp+m*16+g4+r][o = o0+wo+nn*16+r16]
    int oc[4];
    float invc[4], addc[4], ppc[4], ngc[4], awc[4], mwc[4], aac[4], bbc[4];
#pragma unroll
    for (int nn = 0; nn < 4; ++nn) {
      const int o = o0 + wo + nn * 16 + r16;
      oc[nn] = o;
      const float inv = bng[o] / sqrtf(bnv[o] + 1e-5f);
      invc[nn] = inv;
      addc[nn] = bnb[o] - bnm[o] * inv;
      ppc[nn] = pos[o]; ngc[nn] = neg[o];
      awc[nn] = am[o];  mwc[nn] = am[CCH + o];
      aac[nn] = a2[o];  bbc[nn] = b2[o];
    }
    short* tb = (short*)lds;            // [128][136] transpose staging
#pragma unroll
    for (int m = 0; m < 4; ++m) {
#pragma unroll
      for (int r = 0; r < 4; ++r) {
        const int ql = wp + m * 16 + g4 + r;
        const int q = qt + ql;
        const int hh = q / 30, ww2 = q % 30;
        if (hh < HW && ww2 < HW) {
          const float* rrow = rs + (size_t)n * QP + q;
          float tq = 0.f;
#pragma unroll
          for (int kh = 0; kh < 3; ++kh)
#pragma unroll
            for (int kw = 0; kw < 3; ++kw) tq += rrow[kh * 30 + kw];
          const float* xrow = xT + ((size_t)n * PLN + hh * HW + ww2) * CCH;
          float rowsum = 0.f;
#pragma unroll
          for (int nn = 0; nn < 4; ++nn) {
            const int o = oc[nn];
            float v = awc[nn] * (float)acc[m][nn][r] + mwc[nn] * tq;
            v = v * invc[nn] + addc[nn];
            v += xrow[o];
            v = v > 0.f ? ppc[nn] * v : ngc[nn] * v;
            const float xa = (v - bbc[nn]) / aac[nn];
            const float sg = xa > 0.f ? 1.f : (xa < 0.f ? -1.f : 0.f);
            const float bv = sg * aac[nn] + bbc[nn];
            rowsum += bv;
            xpn[((size_t)n * QP + (hh + 1) * 30 + (ww2 + 1)) * CCH + o] =
                (int8_t)__float2int_rn(bv);
            bf16 hb = __float2bfloat16(v);
            tb[(wo + nn * 16 + r16) * 136 + ql] = *reinterpret_cast<short*>(&hb);
          }
          rowsum += __shfl_xor(rowsum, 8); rowsum += __shfl_xor(rowsum, 4);
          rowsum += __shfl_xor(rowsum, 2); rowsum += __shfl_xor(rowsum, 1);
          if (r16 == 0)
            atomicAdd(&rsn[(size_t)n * QP + (hh + 1) * 30 + (ww2 + 1)], rowsum);
        }
      }
    }
    __syncthreads();
    {
      const int o_l = t >> 1, half = t & 1;
      short* x1s = (short*)x1t;
      const size_t gbase = ((size_t)(n * CCH + o0 + o_l)) * QO + qt + half * 64;
#pragma unroll
      for (int j = 0; j < 8; ++j)
        *(short8*)(x1s + gbase + j * 8) = *(const short8*)&tb[o_l * 136 + half * 64 + j * 8];
    }
  } else {
    float* cst = (float*)lds;
    if (t < 128) {
      const int o = o0 + t;
      const float inv = bng[o] / sqrtf(bnv[o] + 1e-5f);
      cst[t]       = am[o] * inv;
      cst[128 + t] = am[CCH + o] * inv;
      cst[256 + t] = bnb[o] - bnm[o] * inv;
      cst[384 + t] = pos[o];
      cst[512 + t] = neg[o];
    }
    __syncthreads();
    const int c16 = lane & 15;
#pragma unroll
    for (int nn = 0; nn < 4; ++nn) {
      const int q = qt + wo + nn * 16 + c16;
      const int hh = q / 30, ww2 = q % 30;
      const bool valid = (hh < HW) && (ww2 < HW);
      const float* rrow = rs + (size_t)n * QP + q;
      float tq = 0.f;
#pragma unroll
      for (int kh = 0; kh < 3; ++kh)
#pragma unroll
        for (int kw = 0; kw < 3; ++kw) tq += rrow[kh * 30 + kw];
#pragma unroll
      for (int m = 0; m < 4; ++m) {
#pragma unroll
        for (int r = 0; r < 4; ++r) {
          const int ol = wp + m * 16 + g4 + r;
          const int o = o0 + ol;
          if (valid) {
            float v = cst[ol] * (float)acc[m][nn][r] + cst[128 + ol] * tq + cst[256 + ol];
            v += __bfloat162float(x1r[((size_t)(n * CCH + o)) * QO + q]);
            v = v > 0.f ? cst[384 + ol] * v : cst[512 + ol] * v;
            out[((size_t)(n * CCH + o)) * PLN + hh * HW + ww2] = v;
          }
        }
      }
    }
  }
}

extern "C" void kernel_launch(void* const* d_in, const int* in_sizes, int n_in,
                              void* d_out, int out_size, void* d_ws, size_t ws_size,
                              hipStream_t stream) {
  const float* x   = (const float*)d_in[0];
  const float* w1  = (const float*)d_in[1];
  const float* al1 = (const float*)d_in[2];
  const float* be1 = (const float*)d_in[3];
  const float* g1  = (const float*)d_in[4];
  const float* bb1 = (const float*)d_in[5];
  const float* m1  = (const float*)d_in[6];
  const float* v1  = (const float*)d_in[7];
  const float* p1  = (const float*)d_in[8];
  const float* n1  = (const float*)d_in[9];
  const float* w2  = (const float*)d_in[10];
  const float* al2 = (const float*)d_in[11];
  const float* be2 = (const float*)d_in[12];
  const float* g2  = (const float*)d_in[13];
  const float* bb2 = (const float*)d_in[14];
  const float* m2  = (const float*)d_in[15];
  const float* v2  = (const float*)d_in[16];
  const float* p2  = (const float*)d_in[17];
  const float* n2  = (const float*)d_in[18];
  float* out = (float*)d_out;

  char* ws = (char*)d_ws;
  int8_t* Xp1 = (int8_t*)(ws);
  int8_t* Xp2 = (int8_t*)(ws + 15728640);
  bf16*   X1T = (bf16*)(ws + 31457280);
  int8_t* Aw1 = (int8_t*)(ws + 60817408);
  int8_t* Aw2 = (int8_t*)(ws + 61407232);
  float*  am1 = (float*)(ws + 61997056);
  float*  am2 = (float*)(ws + 61999104);
  float*  rs1 = (float*)(ws + 62001152);
  float*  rs2 = (float*)(ws + 62246912);
  float*  xT  = out;  // reused as scratch; kconv2 overwrites with final output

  kinit<<<248, 256, 0, stream>>>(Xp1, Xp2, (i32x4*)rs1);
  kwprep<<<512, 256, 0, stream>>>(w1, w2, Aw1, Aw2, am1, am2);
  kaprep<<<NIMG * HW, 256, 0, stream>>>(x, al1, be1, Xp1, rs1, xT);
  kconv<1><<<896, 256, 0, stream>>>(Xp1, Aw1, am1, rs1, g1, bb1, m1, v1, p1, n1,
                                    xT, nullptr, al2, be2, Xp2, X1T, rs2, nullptr);
  kconv<2><<<896, 256, 0, stream>>>(Xp2, Aw2, am2, rs2, g2, bb2, m2, v2, p2, n2,
                                    nullptr, X1T, nullptr, nullptr, nullptr, nullptr,
                                    nullptr, out);
}

// Round 13
// 159.681 us; speedup vs baseline: 5.6061x; 1.0260x over previous
//
#include <hip/hip_runtime.h>
#include <hip/hip_bf16.h>

using bf16 = __hip_bfloat16;
typedef __attribute__((ext_vector_type(8))) short short8;
typedef __attribute__((ext_vector_type(4))) float f32x4;
typedef __attribute__((ext_vector_type(4))) int i32x4;

#define QP   960
#define QO   896
#define KTOT 2304
#define NIMG 64
#define CCH  256
#define HW   28
#define PLN  784

__device__ __forceinline__ void gload_lds16(const void* g, void* l) {
  __builtin_amdgcn_global_load_lds((const __attribute__((address_space(1))) void*)g,
                                   (__attribute__((address_space(3))) void*)l, 16, 0, 0);
}

// ------- init: zero Xp borders/tails (i8) + zero rs1/rs2 --------------------
__global__ __launch_bounds__(256) void kinit(int8_t* __restrict__ xp1,
                                             int8_t* __restrict__ xp2,
                                             i32x4* __restrict__ rsz) {
  const int b = blockIdx.x;
  const int t = threadIdx.x;
  const i32x4 z = {0, 0, 0, 0};
  if (b < 128) {
    const int n = b >> 1;
    int8_t* xp = (b & 1) ? xp2 : xp1;
#pragma unroll
    for (int p = 0; p < 11; ++p) {
      const int task = p * 256 + t;
      const int r = task >> 4, l16 = task & 15;
      int q;
      if (r < 30) q = r;
      else if (r < 60) q = 870 + (r - 30);
      else if (r < 120) q = 900 + (r - 60);
      else { const int k = r - 120; q = (1 + (k >> 1)) * 30 + ((k & 1) ? 29 : 0); }
      ((i32x4*)(xp + ((size_t)n * QP + q) * CCH))[l16] = z;
    }
  } else {
    rsz[(b - 128) * 256 + t] = z;
  }
}

// ---------------- weight prep ------------------------------------------------
__global__ __launch_bounds__(256) void kwprep(const float* __restrict__ w1,
                                              const float* __restrict__ w2,
                                              int8_t* __restrict__ aw1,
                                              int8_t* __restrict__ aw2,
                                              float* __restrict__ am1,
                                              float* __restrict__ am2) {
  const int o = blockIdx.x & 255;
  const float* w = (blockIdx.x >> 8) ? w2 : w1;
  int8_t* aw = (blockIdx.x >> 8) ? aw2 : aw1;
  float* am = (blockIdx.x >> 8) ? am2 : am1;
  const int t = threadIdx.x;
  const int lane = t & 63, wid = t >> 6;
  const float* wo = w + (size_t)o * KTOT;
  float v[9];
  double s = 0.0;
#pragma unroll
  for (int j = 0; j < 9; ++j) { v[j] = wo[t * 9 + j]; s += (double)v[j]; }
  __shared__ double red[4];
#pragma unroll
  for (int m = 32; m >= 1; m >>= 1) s += __shfl_xor(s, m);
  if (lane == 0) red[wid] = s;
  __syncthreads();
  const double mean = (red[0] + red[1] + red[2] + red[3]) * (1.0 / 2304.0);
  __syncthreads();
  double sq = 0.0;
#pragma unroll
  for (int j = 0; j < 9; ++j) { const double d = (double)v[j] - mean; sq += d * d; }
#pragma unroll
  for (int m = 32; m >= 1; m >>= 1) sq += __shfl_xor(sq, m);
  if (lane == 0) red[wid] = sq;
  __syncthreads();
  const double alpha = sqrt((red[0] + red[1] + red[2] + red[3]) * (1.0 / 2304.0));
#pragma unroll
  for (int j = 0; j < 9; ++j) {
    const double d = (double)v[j] - mean;
    const int sg = d > 0.0 ? 1 : (d < 0.0 ? -1 : 0);
    aw[(size_t)o * KTOT + j * CCH + t] = (int8_t)sg;
  }
  if (t == 0) { am[o] = (float)alpha; am[CCH + o] = (float)mean; }
}

// -------- activation signs + row sums + transposed residual -----------------
__global__ __launch_bounds__(256) void kaprep(const float* __restrict__ x,
                                              const float* __restrict__ alpha,
                                              const float* __restrict__ beta,
                                              int8_t* __restrict__ xp,
                                              float* __restrict__ rs,
                                              float* __restrict__ xT) {
  const int n = blockIdx.x / HW;
  const int h = blockIdx.x % HW;
  const int c = threadIdx.x;
  const float a = alpha[c], bt = beta[c];
  const float* src = x + ((size_t)(n * CCH + c)) * PLN + h * HW;
  __shared__ int8_t tile[CCH][HW];
#pragma unroll
  for (int j = 0; j < 7; ++j) {
    float4 f = ((const float4*)src)[j];
    float vv[4] = {f.x, f.y, f.z, f.w};
#pragma unroll
    for (int e = 0; e < 4; ++e) {
      const float xa = (vv[e] - bt) / a;
      const float sg = xa > 0.f ? 1.f : (xa < 0.f ? -1.f : 0.f);
      tile[c][j * 4 + e] = (int8_t)__float2int_rn(sg * a + bt);
      xT[((size_t)n * PLN + h * HW + j * 4 + e) * CCH + c] = vv[e];
    }
  }
  __syncthreads();
  int8_t* dst = xp + ((size_t)n * QP + (h + 1) * 30 + 1) * CCH;
#pragma unroll
  for (int ww = 0; ww < HW; ++ww) dst[ww * CCH + c] = tile[c][ww];
  const int ww = c >> 3, sub = c & 7;
  if (ww < HW) {
    int s = 0;
#pragma unroll
    for (int cc = 0; cc < 32; ++cc) s += (int)tile[sub * 32 + cc][ww];
    s += __shfl_xor(s, 4); s += __shfl_xor(s, 2); s += __shfl_xor(s, 1);
    if (sub == 0) rs[(size_t)n * QP + (h + 1) * 30 + 1 + ww] = (float)s;
  }
}

// ---------------- T[n*QO+q] = 9-tap sum of rs (exact small ints) ------------
__global__ __launch_bounds__(256) void kT(const float* __restrict__ rs,
                                          float* __restrict__ T) {
  const int idx = blockIdx.x * 256 + threadIdx.x;
  const int n = idx / QO, q = idx % QO;
  const float* r = rs + (size_t)n * QP + q;
  float s = 0.f;
#pragma unroll
  for (int kh = 0; kh < 3; ++kh)
#pragma unroll
    for (int kw = 0; kw < 3; ++kw) s += r[kh * 30 + kw];
  T[idx] = s;
}

// ---------------- implicit-GEMM conv: r9 loop + lean epilogue ---------------
// Loop: persistent A (48KB) + cooperative B 3-ring, counted vmcnt(2).
// Epilogue (r13 rewrite): no divides (sign test v>bb, aa>0), T precomputed
// (1 hoisted load/position), Xp2 staged in LDS + vectorized 16B writeout.
template <int EPI>
__global__ __launch_bounds__(256, 2) void kconv(
    const int8_t* __restrict__ xp, const int8_t* __restrict__ aw,
    const float* __restrict__ am, const float* __restrict__ T,
    const float* __restrict__ bng, const float* __restrict__ bnb,
    const float* __restrict__ bnm, const float* __restrict__ bnv,
    const float* __restrict__ pos, const float* __restrict__ neg,
    const float* __restrict__ xT, const bf16* __restrict__ x1r,
    const float* __restrict__ a2, const float* __restrict__ b2,
    int8_t* __restrict__ xpn, bf16* __restrict__ x1t,
    float* __restrict__ rsn, float* __restrict__ out)
{
  __shared__ char lds[73728];           // loop: A 48K @0 + B ring 3*8K @49152
  char* ldsB = lds + 49152;
  const int bid0 = blockIdx.x;
  const int bid = (bid0 & 7) * 112 + (bid0 >> 3);
  const int nt = bid & 1;
  const int mt = bid >> 1;
  const int n = mt / 7;
  const int qt = (mt % 7) * 128;
  const int o0 = nt * 128;
  const int t = threadIdx.x;
  const int lane = t & 63, wid = t >> 6;
  const int wp = (wid >> 1) * 64, wo = (wid & 1) * 64;

  const int rowp = t >> 3;
  const int pcS = t & 7;
  const int cS = pcS ^ (rowp & 7);
  const int pS = cS >> 2;
  const int k16S = cS & 3;

  i32x4 acc[4][4];
#pragma unroll
  for (int i = 0; i < 4; ++i)
#pragma unroll
    for (int j = 0; j < 4; ++j) acc[i][j] = (i32x4){0, 0, 0, 0};

  const int r16 = lane & 15;
  const int g = lane >> 4;
  const int g4 = g * 4;
  const int rsh = r16 >> 1;
  const int pc0 = ((r16 & 1) * 4 + g) ^ rsh;
  const int wpH = (wid >> 1) * 32, woH = (wid & 1) * 32;
  const int qoff = (EPI == 1) ? wp : wo;
  const int ooffH = (EPI == 1) ? woH : wpH;

  const int8_t* baseB = aw + ((size_t)(o0 + 2 * rowp + pS)) * KTOT + k16S * 16;

  auto STAGE_B = [&](int buf, int ks) {
    const int8_t* sB = baseB + (size_t)ks * 64;
    char* dB = ldsB + buf * 8192;
    const int d0 = rowp * 128 + pcS * 16;
    gload_lds16(sB, dB + d0);
    gload_lds16(sB + (size_t)64 * KTOT, dB + 4096 + d0);
  };

  {
    const int8_t* imgA = xp + ((size_t)(n * QP + qt)) * CCH;
#pragma unroll
    for (int i = 0; i < 12; ++i) {
      const int task = t + i * 256;
      if (task < 3040) {
        const int rr = task >> 4, pc = task & 15;
        gload_lds16(imgA + (size_t)rr * CCH + ((pc ^ (rr & 15)) * 16),
                    lds + rr * 256 + pc * 16);
      }
    }
  }
  STAGE_B(0, 0);
  STAGE_B(1, 1);
  asm volatile("s_waitcnt vmcnt(2)" ::: "memory");
  __builtin_amdgcn_s_barrier();

#pragma unroll
  for (int ks = 0; ks < 36; ++ks) {
    const int tap = ks >> 2, ksl = ks & 3;
    const int shc = (tap / 3) * 30 + (tap % 3);
    const int cur = ks % 3;
    const int achunk = ((ksl * 4 + g) ^ ((r16 + shc) & 15)) * 16;
    const char* pAr = lds + (shc + qoff + r16) * 256 + achunk;
    const char* pB = ldsB + cur * 8192;
    i32x4 fP[4], fW[4];
#pragma unroll
    for (int m = 0; m < 4; ++m) {
      fP[m] = *(const i32x4*)&pAr[m * 4096];
      fW[m] = *(const i32x4*)&pB[(ooffH + m * 8 + rsh) * 128 + pc0 * 16];
    }
    if (ks < 34) STAGE_B((ks + 2) % 3, ks + 2);
    __builtin_amdgcn_s_setprio(1);
    if constexpr (EPI == 1) {
#pragma unroll
      for (int m = 0; m < 4; ++m)
#pragma unroll
        for (int nn = 0; nn < 4; ++nn)
          acc[m][nn] = __builtin_amdgcn_mfma_i32_16x16x64_i8(
              fP[m], fW[nn], acc[m][nn], 0, 0, 0);
    } else {
#pragma unroll
      for (int m = 0; m < 4; ++m)
#pragma unroll
        for (int nn = 0; nn < 4; ++nn)
          acc[m][nn] = __builtin_amdgcn_mfma_i32_16x16x64_i8(
              fW[m], fP[nn], acc[m][nn], 0, 0, 0);
    }
    __builtin_amdgcn_s_setprio(0);
    if (ks < 34) {
      asm volatile("s_waitcnt vmcnt(2)" ::: "memory");
    } else {
      asm volatile("s_waitcnt vmcnt(0)" ::: "memory");
    }
    __builtin_amdgcn_s_barrier();
  }

  if constexpr (EPI == 1) {
    // D[q = qt+wp+m*16+g4+r][o = o0+wo+nn*16+r16]
    int oc[4];
    float invc[4], addc[4], ppc[4], ngc[4], awc[4], mwc[4], aac[4], bbc[4];
#pragma unroll
    for (int nn = 0; nn < 4; ++nn) {
      const int o = o0 + wo + nn * 16 + r16;
      oc[nn] = o;
      const float inv = bng[o] / sqrtf(bnv[o] + 1e-5f);
      invc[nn] = inv;
      addc[nn] = bnb[o] - bnm[o] * inv;
      ppc[nn] = pos[o]; ngc[nn] = neg[o];
      awc[nn] = am[o];  mwc[nn] = am[CCH + o];
      aac[nn] = a2[o];  bbc[nn] = b2[o];
    }
    // hoisted T loads (1 per position; was 9-tap recompute = 144 loads)
    float tqv[4][4];
#pragma unroll
    for (int m = 0; m < 4; ++m)
#pragma unroll
      for (int r = 0; r < 4; ++r)
        tqv[m][r] = T[(size_t)n * QO + qt + wp + m * 16 + g4 + r];
    __syncthreads();                    // loop LDS dead; reuse for staging
    short* tb = (short*)lds;            // x1 bf16 [128 o][136 q] @0 (34.8KB)
    int8_t* xpb = (int8_t*)(lds + 36864);  // Xp2 i8 [128 q][128 o] (16KB)
#pragma unroll
    for (int m = 0; m < 4; ++m) {
#pragma unroll
      for (int r = 0; r < 4; ++r) {
        const int ql = wp + m * 16 + g4 + r;
        const int q = qt + ql;
        const int hh = q / 30, ww2 = q % 30;
        if (hh < HW && ww2 < HW) {
          const float tq = tqv[m][r];
          const float* xrow = xT + ((size_t)n * PLN + hh * HW + ww2) * CCH;
          float rowsum = 0.f;
#pragma unroll
          for (int nn = 0; nn < 4; ++nn) {
            const int ol = wo + nn * 16 + r16;
            float v = awc[nn] * (float)acc[m][nn][r] + mwc[nn] * tq;
            v = v * invc[nn] + addc[nn];
            v += xrow[oc[nn]];
            v = v > 0.f ? ppc[nn] * v : ngc[nn] * v;
            // sign((v-bb)/aa) == sign(v-bb) since aa>0  -> no divide
            const float d = v - bbc[nn];
            const float sg = d > 0.f ? 1.f : (d < 0.f ? -1.f : 0.f);
            const float bv = sg * aac[nn] + bbc[nn];
            rowsum += bv;
            xpb[ql * 128 + ol] = (int8_t)__float2int_rn(bv);
            bf16 hb = __float2bfloat16(v);
            tb[ol * 136 + ql] = *reinterpret_cast<short*>(&hb);
          }
          rowsum += __shfl_xor(rowsum, 8); rowsum += __shfl_xor(rowsum, 4);
          rowsum += __shfl_xor(rowsum, 2); rowsum += __shfl_xor(rowsum, 1);
          if (r16 == 0)
            atomicAdd(&rsn[(size_t)n * QP + (hh + 1) * 30 + (ww2 + 1)], rowsum);
        }
      }
    }
    __syncthreads();
    // x1T transpose readout: coalesced 16B
    {
      const int o_l = t >> 1, half = t & 1;
      short* x1s = (short*)x1t;
      const size_t gbase = ((size_t)(n * CCH + o0 + o_l)) * QO + qt + half * 64;
#pragma unroll
      for (int j = 0; j < 8; ++j)
        *(short8*)(x1s + gbase + j * 8) = *(const short8*)&tb[o_l * 136 + half * 64 + j * 8];
    }
    // Xp2 vectorized writeout: 4 x 16B per thread (was 64 byte-stores/lane)
    {
      const int row = t >> 1, half = t & 1;
      const int q = qt + row;
      const int hh = q / 30, ww2 = q % 30;
      if (hh < HW && ww2 < HW) {
        int8_t* dst = xpn + ((size_t)n * QP + (hh + 1) * 30 + (ww2 + 1)) * CCH
                      + o0 + half * 64;
        const int8_t* srcl = xpb + row * 128 + half * 64;
#pragma unroll
        for (int j = 0; j < 4; ++j)
          *(i32x4*)(dst + j * 16) = *(const i32x4*)(srcl + j * 16);
      }
    }
  } else {
    float* cst = (float*)lds;
    if (t < 128) {
      const int o = o0 + t;
      const float inv = bng[o] / sqrtf(bnv[o] + 1e-5f);
      cst[t]       = am[o] * inv;
      cst[128 + t] = am[CCH + o] * inv;
      cst[256 + t] = bnb[o] - bnm[o] * inv;
      cst[384 + t] = pos[o];
      cst[512 + t] = neg[o];
    }
    const int c16 = lane & 15;
    // hoisted T loads: q depends only on nn (and c16)
    float tqv[4];
#pragma unroll
    for (int nn = 0; nn < 4; ++nn)
      tqv[nn] = T[(size_t)n * QO + qt + wo + nn * 16 + c16];
    __syncthreads();
#pragma unroll
    for (int nn = 0; nn < 4; ++nn) {
      const int q = qt + wo + nn * 16 + c16;
      const int hh = q / 30, ww2 = q % 30;
      const bool valid = (hh < HW) && (ww2 < HW);
      const float tq = tqv[nn];
#pragma unroll
      for (int m = 0; m < 4; ++m) {
#pragma unroll
        for (int r = 0; r < 4; ++r) {
          const int ol = wp + m * 16 + g4 + r;
          const int o = o0 + ol;
          if (valid) {
            float v = cst[ol] * (float)acc[m][nn][r] + cst[128 + ol] * tq + cst[256 + ol];
            v += __bfloat162float(x1r[((size_t)(n * CCH + o)) * QO + q]);
            v = v > 0.f ? cst[384 + ol] * v : cst[512 + ol] * v;
            out[((size_t)(n * CCH + o)) * PLN + hh * HW + ww2] = v;
          }
        }
      }
    }
  }
}

extern "C" void kernel_launch(void* const* d_in, const int* in_sizes, int n_in,
                              void* d_out, int out_size, void* d_ws, size_t ws_size,
                              hipStream_t stream) {
  const float* x   = (const float*)d_in[0];
  const float* w1  = (const float*)d_in[1];
  const float* al1 = (const float*)d_in[2];
  const float* be1 = (const float*)d_in[3];
  const float* g1  = (const float*)d_in[4];
  const float* bb1 = (const float*)d_in[5];
  const float* m1  = (const float*)d_in[6];
  const float* v1  = (const float*)d_in[7];
  const float* p1  = (const float*)d_in[8];
  const float* n1  = (const float*)d_in[9];
  const float* w2  = (const float*)d_in[10];
  const float* al2 = (const float*)d_in[11];
  const float* be2 = (const float*)d_in[12];
  const float* g2  = (const float*)d_in[13];
  const float* bb2 = (const float*)d_in[14];
  const float* m2  = (const float*)d_in[15];
  const float* v2  = (const float*)d_in[16];
  const float* p2  = (const float*)d_in[17];
  const float* n2  = (const float*)d_in[18];
  float* out = (float*)d_out;

  char* ws = (char*)d_ws;
  // workspace layout:
  //   Xp1 @0, Xp2 @15728640 (i8 [64][960][256])
  //   x1T @31457280 (bf16 [64][256][896])
  //   Aw1 @60817408, Aw2 @61407232 (i8 [256][2304])
  //   am1 @61997056, am2 @61999104
  //   rs1 @62001152, rs2 @62246912 (f32 [64][960])
  //   Tb  @62492672 (f32 [64][896])          (total 62,722,048)
  int8_t* Xp1 = (int8_t*)(ws);
  int8_t* Xp2 = (int8_t*)(ws + 15728640);
  bf16*   X1T = (bf16*)(ws + 31457280);
  int8_t* Aw1 = (int8_t*)(ws + 60817408);
  int8_t* Aw2 = (int8_t*)(ws + 61407232);
  float*  am1 = (float*)(ws + 61997056);
  float*  am2 = (float*)(ws + 61999104);
  float*  rs1 = (float*)(ws + 62001152);
  float*  rs2 = (float*)(ws + 62246912);
  float*  Tb  = (float*)(ws + 62492672);
  float*  xT  = out;  // scratch; kconv2 overwrites with final output

  kinit<<<248, 256, 0, stream>>>(Xp1, Xp2, (i32x4*)rs1);
  kwprep<<<512, 256, 0, stream>>>(w1, w2, Aw1, Aw2, am1, am2);
  kaprep<<<NIMG * HW, 256, 0, stream>>>(x, al1, be1, Xp1, rs1, xT);
  kT<<<NIMG * QO / 256, 256, 0, stream>>>(rs1, Tb);
  kconv<1><<<896, 256, 0, stream>>>(Xp1, Aw1, am1, Tb, g1, bb1, m1, v1, p1, n1,
                                    xT, nullptr, al2, be2, Xp2, X1T, rs2, nullptr);
  kT<<<NIMG * QO / 256, 256, 0, stream>>>(rs2, Tb);
  kconv<2><<<896, 256, 0, stream>>>(Xp2, Aw2, am2, Tb, g2, bb2, m2, v2, p2, n2,
                                    nullptr, X1T, nullptr, nullptr, nullptr, nullptr,
                                    nullptr, out);
}